// Round 8
// baseline (907.239 us; speedup 1.0000x reference)
//
#include <hip/hip_runtime.h>

#define BB 4
#define NN 4096
#define DD 256
#define KK 16
#define PTS 2
#define SA 280   // bufA/bufB row stride (bf16)
#define SE 96    // emb row stride

typedef __bf16 bf16;
typedef __attribute__((ext_vector_type(8))) __bf16 bf16x8;
typedef __attribute__((ext_vector_type(4))) __bf16 bf16x4;
typedef __attribute__((ext_vector_type(4))) float f32x4;

#define KNNB 4096   // knn blocks (4 points each)
#define PROJB 256   // proj blocks (64 rows each)
#define PREPB 256   // prep blocks

// ---------------------------------------------------------------------------
// setup_kernel: knn (xyz staged in LDS) + proj (64 rows/block, f32 weights
// inline-converted) + prep (w1/w2/pe_w -> bf16, zero bn sums). No inter-block
// dependencies: proj reads raw f32 weights, knn reads raw xyz.
// Grid: [0,KNNB) knn | [KNNB,KNNB+PROJB) proj | rest prep.
// ---------------------------------------------------------------------------
__global__ __launch_bounds__(256, 2) void setup_kernel(
    const float* __restrict__ xyz, const float* __restrict__ feats,
    const float* __restrict__ w_q, const float* __restrict__ w_k,
    const float* __restrict__ w_v, const float* __restrict__ g_w1,
    const float* __restrict__ g_w2, const float* __restrict__ pe_w,
    int* __restrict__ knn, bf16* __restrict__ qb, bf16* __restrict__ kfb,
    bf16* __restrict__ vfb, bf16* __restrict__ w1b, bf16* __restrict__ w2b,
    bf16* __restrict__ pwb, float* __restrict__ sums) {
  const int bid = blockIdx.x;
  const int t = threadIdx.x;
  __shared__ __align__(16) float smem[NN * 3];  // 48 KB (knn) / proj fs union

  if (bid < KNNB) {
    // ---- knn: 4 points/block; xyz[b] staged once into LDS ----
    const int row0 = bid * 4;
    const int b = row0 >> 12;
    const float* xb = xyz + (size_t)b * NN * 3;
    for (int e = t; e < NN * 3; e += 256) smem[e] = xb[e];
    __syncthreads();
    const int lane = t & 63;
    const int row = row0 + (t >> 6);
    const int i = row & (NN - 1);
    const float xi = smem[i * 3 + 0], yi = smem[i * 3 + 1], zi = smem[i * 3 + 2];
    unsigned long long cand[64];
#pragma unroll
    for (int c = 0; c < 64; ++c) {
      const int j = c * 64 + lane;
      const float dx = xi - smem[j * 3 + 0];
      const float dy = yi - smem[j * 3 + 1];
      const float dz = zi - smem[j * 3 + 2];
      const float d = dx * dx + dy * dy + dz * dz;
      const unsigned long long fb =
          (unsigned long long)(__float_as_uint(d)) + 1ull;
      cand[c] = (fb << 32) | (unsigned int)j;
    }
    unsigned long long gm[8];
#pragma unroll
    for (int g = 0; g < 8; ++g) {
      unsigned long long mn = cand[g * 8];
#pragma unroll
      for (int s = 1; s < 8; ++s)
        if (cand[g * 8 + s] < mn) mn = cand[g * 8 + s];
      gm[g] = mn;
    }
    unsigned int myj = 0u;
    for (int r = 0; r < KK; ++r) {
      unsigned long long lmin = gm[0];
#pragma unroll
      for (int g = 1; g < 8; ++g)
        if (gm[g] < lmin) lmin = gm[g];
#pragma unroll
      for (int off = 1; off < 64; off <<= 1) {
        const unsigned long long o = __shfl_xor(lmin, off);
        if (o < lmin) lmin = o;
      }
      if (lane == r) myj = (unsigned int)lmin;
#pragma unroll
      for (int g = 0; g < 8; ++g) {
        if (__ballot(gm[g] == lmin)) {
          unsigned long long nm = ~0ull;
#pragma unroll
          for (int s = 0; s < 8; ++s) {
            const unsigned long long v = cand[g * 8 + s];
            if (v > lmin && v < nm) nm = v;
          }
          if (gm[g] == lmin) gm[g] = nm;
        }
      }
    }
    if (lane < KK) knn[row * KK + lane] = (int)myj;
    return;
  }
  if (bid < KNNB + PROJB) {
    // ---- proj: 64 rows/block MFMA; f32 weights converted inline ----
    bf16(*fs)[264] = (bf16(*)[264])smem;  // 64*264*2 = 33.8 KB
    const int lane = t & 63, wv = t >> 6;
    const int m = lane & 15, qd = lane >> 4;
    const size_t r0 = (size_t)(bid - KNNB) * 64;
    const float4* f4 = (const float4*)(feats + r0 * DD);
#pragma unroll
    for (int i = 0; i < 16; ++i) {
      const int e = i * 256 + t;  // 4096 float4 slots
      const float4 v = f4[e];
      bf16x4 w;
      w[0] = (bf16)v.x; w[1] = (bf16)v.y; w[2] = (bf16)v.z; w[3] = (bf16)v.w;
      *(bf16x4*)&fs[e >> 6][(e & 63) * 4] = w;
    }
    __syncthreads();
    bf16x8 afrag[8];
#pragma unroll
    for (int f = 0; f < 8; ++f)
      afrag[f] = *(const bf16x8*)&fs[wv * 16 + m][f * 32 + qd * 8];
    const float* wmat[3] = {w_q, w_k, w_v};
    bf16* omat[3] = {qb, kfb, vfb};
    for (int mat = 0; mat < 3; ++mat) {
      const float* wb = wmat[mat];
      for (int nt = 0; nt < 16; ++nt) {
        const int n = nt * 16 + m;
        bf16x8 bfr[8];
#pragma unroll
        for (int f = 0; f < 8; ++f) {
          const float4 wa =
              *(const float4*)(wb + (size_t)n * DD + f * 32 + qd * 8);
          const float4 wc =
              *(const float4*)(wb + (size_t)n * DD + f * 32 + qd * 8 + 4);
          bf16x8 x;
          x[0] = (bf16)wa.x; x[1] = (bf16)wa.y; x[2] = (bf16)wa.z; x[3] = (bf16)wa.w;
          x[4] = (bf16)wc.x; x[5] = (bf16)wc.y; x[6] = (bf16)wc.z; x[7] = (bf16)wc.w;
          bfr[f] = x;
        }
        f32x4 c = {0.f, 0.f, 0.f, 0.f};
#pragma unroll
        for (int f = 0; f < 8; ++f)
          c = __builtin_amdgcn_mfma_f32_16x16x32_bf16(afrag[f], bfr[f], c, 0, 0, 0);
#pragma unroll
        for (int rr = 0; rr < 4; ++rr)
          omat[mat][(r0 + wv * 16 + qd * 4 + rr) * DD + n] = (bf16)c[rr];
      }
    }
    return;
  }
  // ---- prep ----
  {
    const int idx = (bid - (KNNB + PROJB)) * 256 + t;  // 65536
    w1b[idx] = (bf16)g_w1[idx];
    w2b[idx] = (bf16)g_w2[idx];
    if (idx < 256 * 64) {
      const int n = idx >> 6, c = idx & 63;
      pwb[idx] = (c < 33) ? (bf16)pe_w[n * 33 + c] : (bf16)0.f;
    }
    if (idx < 2 * DD) sums[idx] = 0.f;
  }
}

// ---------------------------------------------------------------------------
// edge_v8 = v7 compute structure, widened to 512 threads / 8 waves per block
// (each wave owns 32 output cols, tt in {0,1}). Halves per-thread live regs
// (vpe 16, afrag 16) so __launch_bounds__(512,6) (VGPR cap 85) holds without
// spills -> target ~24 waves/CU vs v7's ~10.7 for gather-latency hiding.
// Inline scalar gathers (best measured); fused BN partial-stats epilogue.
// LDS: bufA 17.9K + union(emb 6K | bufB 17.9K) + js ~= 36 KB.
// ---------------------------------------------------------------------------
__global__ __launch_bounds__(512, 6) void edge_v8(
    const float* __restrict__ xyz, const float* __restrict__ feats,
    const bf16* __restrict__ qb, const bf16* __restrict__ kfb,
    const bf16* __restrict__ vfb, const int* __restrict__ knn,
    const bf16* __restrict__ w1b, const float* __restrict__ g_b1,
    const bf16* __restrict__ w2b, const float* __restrict__ g_b2,
    const bf16* __restrict__ pwb, const float* __restrict__ pe_b,
    float* __restrict__ res, float* __restrict__ sums,
    float* __restrict__ sumsq) {
  const int t = threadIdx.x;
  const int lane = t & 63;
  const int wv = t >> 6;  // 0..7
  const int m = lane & 15;
  const int qd = lane >> 4;
  const int row0 = blockIdx.x * PTS;
  const int b = row0 >> 12;

  __shared__ __align__(16) bf16 bufA[PTS][16][SA];        // edges
  __shared__ __align__(16) char un_s[PTS * 16 * SA * 2];  // emb | bufB(h)
  bf16(*bufB)[16][SA] = (bf16(*)[16][SA])un_s;
  bf16(*emb_s)[16][SE] = (bf16(*)[16][SE])un_s;
  __shared__ int js_s[PTS][16];

  if (t < PTS * 16) js_s[t >> 4][t & 15] = knn[(row0 + (t >> 4)) * KK + (t & 15)];
  __syncthreads();

  // ---- emb fill: thread t -> neighbor k=t>>5, cols (t&31)*3..+2 ----
  const float* xb = xyz + (size_t)b * NN * 3;
  {
    const int k = t >> 5;
    const int c0 = (t & 31) * 3;
#pragma unroll
    for (int p = 0; p < PTS; ++p) {
      const int i = (row0 + p) & (NN - 1);
      const int j = js_s[p][k];
#pragma unroll
      for (int cc = 0; cc < 3; ++cc) {
        const int c = c0 + cc;
        float val = 0.f;
        if (c < 33) {
          const int ax = (c < 3) ? c : (c - 3) % 3;
          const float pd = xb[i * 3 + ax] - xb[j * 3 + ax];
          if (c < 3) {
            val = pd;
          } else {
            const int f = (c - 3) / 6;
            const float x = pd * fmaf(7.75f, (float)f, 1.0f);  // linspace(1,32,5)
            val = (((c - 3) % 6) < 3) ? __sinf(x) : __cosf(x);
          }
        }
        emb_s[p][k][c] = (bf16)val;
      }
    }
  }
  __syncthreads();

  // ---- phase B: pe MFMA -> bufA = q - k + pe ; vpe regs (exact f32) ----
  float vpe[2][PTS][4];
  bf16x8 ea0[PTS], ea1[PTS];
#pragma unroll
  for (int p = 0; p < PTS; ++p) {
    ea0[p] = *(const bf16x8*)&emb_s[p][m][qd * 8];
    ea1[p] = *(const bf16x8*)&emb_s[p][m][32 + qd * 8];
  }
#pragma unroll
  for (int tt = 0; tt < 2; ++tt) {
    const int n = wv * 32 + tt * 16 + m;
    const bf16x8 b0 = *(const bf16x8*)(pwb + (size_t)n * 64 + qd * 8);
    const bf16x8 b1 = *(const bf16x8*)(pwb + (size_t)n * 64 + 32 + qd * 8);
    const float bias = pe_b[n];
#pragma unroll
    for (int p = 0; p < PTS; ++p) {
      f32x4 c = {bias, bias, bias, bias};
      c = __builtin_amdgcn_mfma_f32_16x16x32_bf16(ea0[p], b0, c, 0, 0, 0);
      c = __builtin_amdgcn_mfma_f32_16x16x32_bf16(ea1[p], b1, c, 0, 0, 0);
      const float qv = (float)qb[(size_t)(row0 + p) * DD + n];
#pragma unroll
      for (int rr = 0; rr < 4; ++rr) {
        const int krow = qd * 4 + rr;
        const size_t jr = ((size_t)(b * NN + js_s[p][krow])) * DD + n;
        bufA[p][krow][n] = (bf16)(qv - (float)kfb[jr] + c[rr]);
        vpe[tt][p][rr] = (float)vfb[jr] + c[rr];
      }
    }
  }
  __syncthreads();  // bufA ready; emb reads done (union -> bufB safe)

  // ---- layer 1: h = relu(edges @ W1^T + b1), bufA -> bufB ----
  {
    bf16x8 afrag[PTS][8];
#pragma unroll
    for (int p = 0; p < PTS; ++p)
#pragma unroll
      for (int f = 0; f < 8; ++f)
        afrag[p][f] = *(const bf16x8*)&bufA[p][m][f * 32 + qd * 8];
    for (int tt = 0; tt < 2; ++tt) {
      const int n = wv * 32 + tt * 16 + m;
      bf16x8 bfr[8];
#pragma unroll
      for (int f = 0; f < 8; ++f)
        bfr[f] = *(const bf16x8*)(w1b + (size_t)n * DD + f * 32 + qd * 8);
      const float bias = g_b1[n];
#pragma unroll
      for (int p = 0; p < PTS; ++p) {
        f32x4 c = {bias, bias, bias, bias};
#pragma unroll
        for (int f = 0; f < 8; ++f)
          c = __builtin_amdgcn_mfma_f32_16x16x32_bf16(afrag[p][f], bfr[f], c, 0, 0, 0);
#pragma unroll
        for (int rr = 0; rr < 4; ++rr)
          bufB[p][qd * 4 + rr][n] = (bf16)fmaxf(c[rr], 0.f);
      }
    }
  }
  __syncthreads();

  // ---- layer 2 + softmax over k + combine + fused BN partial stats ----
  {
    bf16x8 afrag[PTS][8];
#pragma unroll
    for (int p = 0; p < PTS; ++p)
#pragma unroll
      for (int f = 0; f < 8; ++f)
        afrag[p][f] = *(const bf16x8*)&bufB[p][m][f * 32 + qd * 8];
#pragma unroll
    for (int tt = 0; tt < 2; ++tt) {
      const int n = wv * 32 + tt * 16 + m;
      bf16x8 bfr[8];
#pragma unroll
      for (int f = 0; f < 8; ++f)
        bfr[f] = *(const bf16x8*)(w2b + (size_t)n * DD + f * 32 + qd * 8);
      const float bias = g_b2[n];
      float bs = 0.f, bs2 = 0.f;
#pragma unroll
      for (int p = 0; p < PTS; ++p) {
        f32x4 c = {bias, bias, bias, bias};
#pragma unroll
        for (int f = 0; f < 8; ++f)
          c = __builtin_amdgcn_mfma_f32_16x16x32_bf16(afrag[p][f], bfr[f], c, 0, 0, 0);
        float mx = fmaxf(fmaxf(c[0], c[1]), fmaxf(c[2], c[3]));
        mx = fmaxf(mx, __shfl_xor(mx, 16));
        mx = fmaxf(mx, __shfl_xor(mx, 32));
        float e[4], den = 0.f;
#pragma unroll
        for (int rr = 0; rr < 4; ++rr) {
          e[rr] = __expf(c[rr] - mx);
          den += e[rr];
        }
        den += __shfl_xor(den, 16);
        den += __shfl_xor(den, 32);
        float num = 0.f;
#pragma unroll
        for (int rr = 0; rr < 4; ++rr) num += e[rr] * vpe[tt][p][rr];
        num += __shfl_xor(num, 16);
        num += __shfl_xor(num, 32);
        if (qd == 0) {
          const size_t o = (size_t)(row0 + p) * DD + n;
          const float out = num / den + feats[o];
          res[o] = out;
          bs += out;
          bs2 += out * out;
        }
      }
      if (qd == 0) {
        atomicAdd(&sums[n], bs);
        atomicAdd(&sumsq[n], bs2);
      }
    }
  }
}

// ---------------------------------------------------------------------------
// BatchNorm apply (stats accumulated by edge_v8's epilogue)
// ---------------------------------------------------------------------------
__global__ __launch_bounds__(256) void bn_apply(float* __restrict__ out,
                                                const float* __restrict__ sums,
                                                const float* __restrict__ sumsq,
                                                const float* __restrict__ bn_w,
                                                const float* __restrict__ bn_b) {
  const int idx = blockIdx.x * 256 + threadIdx.x;
  const int c = idx & (DD - 1);
  const float inv_n = 1.f / (float)(BB * NN);
  const float mean = sums[c] * inv_n;
  const float var = sumsq[c] * inv_n - mean * mean;
  const float v = out[idx];
  out[idx] = (v - mean) * rsqrtf(var + 1e-5f) * bn_w[c] + bn_b[c];
}

extern "C" void kernel_launch(void* const* d_in, const int* in_sizes, int n_in,
                              void* d_out, int out_size, void* d_ws,
                              size_t ws_size, hipStream_t stream) {
  (void)in_sizes; (void)n_in; (void)out_size; (void)ws_size;
  const float* xyz = (const float*)d_in[0];
  const float* feats = (const float*)d_in[1];
  const float* w_q = (const float*)d_in[2];
  const float* w_k = (const float*)d_in[3];
  const float* w_v = (const float*)d_in[4];
  const float* g_w1 = (const float*)d_in[5];
  const float* g_b1 = (const float*)d_in[6];
  const float* g_w2 = (const float*)d_in[7];
  const float* g_b2 = (const float*)d_in[8];
  const float* pe_w = (const float*)d_in[9];
  const float* pe_b = (const float*)d_in[10];
  const float* bn_w = (const float*)d_in[11];
  const float* bn_b = (const float*)d_in[12];
  float* out = (float*)d_out;

  const int BN = BB * NN;  // 16384
  char* w = (char*)d_ws;
  int* knn = (int*)w;       w += (size_t)BN * KK * 4;
  bf16* qb = (bf16*)w;      w += (size_t)BN * DD * 2;
  bf16* kfb = (bf16*)w;     w += (size_t)BN * DD * 2;
  bf16* vfb = (bf16*)w;     w += (size_t)BN * DD * 2;
  float* sums = (float*)w;  w += DD * 4;
  float* sumsq = (float*)w; w += DD * 4;
  bf16* w1b = (bf16*)w;     w += (size_t)DD * DD * 2;
  bf16* w2b = (bf16*)w;     w += (size_t)DD * DD * 2;
  bf16* pwb = (bf16*)w;     w += (size_t)DD * 64 * 2;

  setup_kernel<<<KNNB + PROJB + PREPB, 256, 0, stream>>>(
      xyz, feats, w_q, w_k, w_v, g_w1, g_w2, pe_w, knn, qb, kfb, vfb, w1b, w2b,
      pwb, sums);
  edge_v8<<<BN / PTS, 512, 0, stream>>>(xyz, feats, qb, kfb, vfb, knn, w1b,
                                        g_b1, w2b, g_b2, pwb, pe_b, out, sums,
                                        sumsq);
  bn_apply<<<BN, 256, 0, stream>>>(out, sums, sumsq, bn_w, bn_b);
}

// Round 11
// 606.784 us; speedup vs baseline: 1.4952x; 1.4952x over previous
//
#include <hip/hip_runtime.h>

#define BB 4
#define NN 4096
#define DD 256
#define KK 16
#define PTS 2
#define SA 264   // bufA/bufB/kf/vf row stride (bf16)

typedef __bf16 bf16;
typedef __attribute__((ext_vector_type(8))) __bf16 bf16x8;
typedef __attribute__((ext_vector_type(4))) __bf16 bf16x4;
typedef __attribute__((ext_vector_type(4))) float f32x4;

#define KNNB 4096   // knn blocks (4 points each)
#define PROJB 256   // proj blocks (64 rows each)
#define PREPB 256   // prep blocks

// ---------------------------------------------------------------------------
// setup_kernel (R8 version, measured ~equal to R7's): knn (xyz in LDS) +
// proj (64 rows/block, f32 weights inline-converted) + prep.
// ---------------------------------------------------------------------------
__global__ __launch_bounds__(256, 2) void setup_kernel(
    const float* __restrict__ xyz, const float* __restrict__ feats,
    const float* __restrict__ w_q, const float* __restrict__ w_k,
    const float* __restrict__ w_v, const float* __restrict__ g_w1,
    const float* __restrict__ g_w2, const float* __restrict__ pe_w,
    int* __restrict__ knn, bf16* __restrict__ qb, bf16* __restrict__ kfb,
    bf16* __restrict__ vfb, bf16* __restrict__ w1b, bf16* __restrict__ w2b,
    bf16* __restrict__ pwb, float* __restrict__ sums) {
  const int bid = blockIdx.x;
  const int t = threadIdx.x;
  __shared__ __align__(16) float smem[NN * 3];  // 48 KB knn / proj fs union

  if (bid < KNNB) {
    const int row0 = bid * 4;
    const int b = row0 >> 12;
    const float* xb = xyz + (size_t)b * NN * 3;
    for (int e = t; e < NN * 3; e += 256) smem[e] = xb[e];
    __syncthreads();
    const int lane = t & 63;
    const int row = row0 + (t >> 6);
    const int i = row & (NN - 1);
    const float xi = smem[i * 3 + 0], yi = smem[i * 3 + 1], zi = smem[i * 3 + 2];
    unsigned long long cand[64];
#pragma unroll
    for (int c = 0; c < 64; ++c) {
      const int j = c * 64 + lane;
      const float dx = xi - smem[j * 3 + 0];
      const float dy = yi - smem[j * 3 + 1];
      const float dz = zi - smem[j * 3 + 2];
      const float d = dx * dx + dy * dy + dz * dz;
      const unsigned long long fb =
          (unsigned long long)(__float_as_uint(d)) + 1ull;
      cand[c] = (fb << 32) | (unsigned int)j;
    }
    unsigned long long gm[8];
#pragma unroll
    for (int g = 0; g < 8; ++g) {
      unsigned long long mn = cand[g * 8];
#pragma unroll
      for (int s = 1; s < 8; ++s)
        if (cand[g * 8 + s] < mn) mn = cand[g * 8 + s];
      gm[g] = mn;
    }
    unsigned int myj = 0u;
    for (int r = 0; r < KK; ++r) {
      unsigned long long lmin = gm[0];
#pragma unroll
      for (int g = 1; g < 8; ++g)
        if (gm[g] < lmin) lmin = gm[g];
#pragma unroll
      for (int off = 1; off < 64; off <<= 1) {
        const unsigned long long o = __shfl_xor(lmin, off);
        if (o < lmin) lmin = o;
      }
      if (lane == r) myj = (unsigned int)lmin;
#pragma unroll
      for (int g = 0; g < 8; ++g) {
        if (__ballot(gm[g] == lmin)) {
          unsigned long long nm = ~0ull;
#pragma unroll
          for (int s = 0; s < 8; ++s) {
            const unsigned long long v = cand[g * 8 + s];
            if (v > lmin && v < nm) nm = v;
          }
          if (gm[g] == lmin) gm[g] = nm;
        }
      }
    }
    if (lane < KK) knn[row * KK + lane] = (int)myj;
    return;
  }
  if (bid < KNNB + PROJB) {
    bf16(*fs)[SA] = (bf16(*)[SA])smem;  // 64*264*2 = 33.8 KB
    const int lane = t & 63, wv = t >> 6;
    const int m = lane & 15, qd = lane >> 4;
    const size_t r0 = (size_t)(bid - KNNB) * 64;
    const float4* f4 = (const float4*)(feats + r0 * DD);
#pragma unroll
    for (int i = 0; i < 16; ++i) {
      const int e = i * 256 + t;
      const float4 v = f4[e];
      bf16x4 w;
      w[0] = (bf16)v.x; w[1] = (bf16)v.y; w[2] = (bf16)v.z; w[3] = (bf16)v.w;
      *(bf16x4*)&fs[e >> 6][(e & 63) * 4] = w;
    }
    __syncthreads();
    bf16x8 afrag[8];
#pragma unroll
    for (int f = 0; f < 8; ++f)
      afrag[f] = *(const bf16x8*)&fs[wv * 16 + m][f * 32 + qd * 8];
    const float* wmat[3] = {w_q, w_k, w_v};
    bf16* omat[3] = {qb, kfb, vfb};
    for (int mat = 0; mat < 3; ++mat) {
      const float* wb = wmat[mat];
      for (int nt = 0; nt < 16; ++nt) {
        const int n = nt * 16 + m;
        bf16x8 bfr[8];
#pragma unroll
        for (int f = 0; f < 8; ++f) {
          const float4 wa =
              *(const float4*)(wb + (size_t)n * DD + f * 32 + qd * 8);
          const float4 wc =
              *(const float4*)(wb + (size_t)n * DD + f * 32 + qd * 8 + 4);
          bf16x8 x;
          x[0] = (bf16)wa.x; x[1] = (bf16)wa.y; x[2] = (bf16)wa.z; x[3] = (bf16)wa.w;
          x[4] = (bf16)wc.x; x[5] = (bf16)wc.y; x[6] = (bf16)wc.z; x[7] = (bf16)wc.w;
          bfr[f] = x;
        }
        f32x4 c = {0.f, 0.f, 0.f, 0.f};
#pragma unroll
        for (int f = 0; f < 8; ++f)
          c = __builtin_amdgcn_mfma_f32_16x16x32_bf16(afrag[f], bfr[f], c, 0, 0, 0);
#pragma unroll
        for (int rr = 0; rr < 4; ++rr)
          omat[mat][(r0 + wv * 16 + qd * 4 + rr) * DD + n] = (bf16)c[rr];
      }
    }
    return;
  }
  {
    const int idx = (bid - (KNNB + PROJB)) * 256 + t;  // 65536
    w1b[idx] = (bf16)g_w1[idx];
    w2b[idx] = (bf16)g_w2[idx];
    if (idx < 256 * 64) {
      const int n = idx >> 6, c = idx & 63;
      pwb[idx] = (c < 33) ? (bf16)pe_w[n * 33 + c] : (bf16)0.f;
    }
    if (idx < 2 * DD) sums[idx] = 0.f;
  }
}

// per-lane positional-embedding value for column c (0..32; >32 -> 0)
__device__ __forceinline__ float embval(int c, float pd0, float pd1, float pd2) {
  if (c > 32) return 0.f;
  const int cm = c - 3;
  const int ax = (c < 3) ? c : cm % 3;
  const float pdv = (ax == 0) ? pd0 : ((ax == 1) ? pd1 : pd2);
  if (c < 3) return pdv;
  const int f = cm / 6;
  const float x = pdv * fmaf(7.75f, (float)f, 1.0f);  // linspace(1,32,5)
  return ((cm % 6) < 3) ? __sinf(x) : __cosf(x);
}

// ---------------------------------------------------------------------------
// edge_v9: v7 compute at (256,3) but BOTH gather streams vectorized:
//  - kf_s + vf_s staged via 16B bf16x8 loads (8 chunks/thread) right after
//    the js barrier -> gather lane-addresses drop ~8x (TCP-address model)
//  - emb computed per-lane directly into A-frag registers (no emb_s LDS)
//  - pe kept in 32 f32 regs (replaces vpe: net-zero VGPR); epilogue reads
//    vf_s from LDS
//  - kf_s unions with bufB (kf dead at the phase-B barrier)
// LDS: bufA 16.9K + union(kf_s|bufB) 16.9K + vf_s 16.9K + js ~= 50.9K
//   -> 3 blocks/CU at natural VGPR (~90). Fused BN partial-stats epilogue.
// ---------------------------------------------------------------------------
__global__ __launch_bounds__(256, 3) void edge_v9(
    const float* __restrict__ xyz, const float* __restrict__ feats,
    const bf16* __restrict__ qb, const bf16* __restrict__ kfb,
    const bf16* __restrict__ vfb, const int* __restrict__ knn,
    const bf16* __restrict__ w1b, const float* __restrict__ g_b1,
    const bf16* __restrict__ w2b, const float* __restrict__ g_b2,
    const bf16* __restrict__ pwb, const float* __restrict__ pe_b,
    float* __restrict__ res, float* __restrict__ sums,
    float* __restrict__ sumsq) {
  const int t = threadIdx.x;
  const int lane = t & 63;
  const int wv = t >> 6;
  const int m = lane & 15;
  const int qd = lane >> 4;
  const int row0 = blockIdx.x * PTS;
  const int b = row0 >> 12;

  __shared__ __align__(16) bf16 bufA[PTS][16][SA];        // edges
  __shared__ __align__(16) char un_s[PTS * 16 * SA * 2];  // kf_s | bufB(h)
  bf16(*bufB)[16][SA] = (bf16(*)[16][SA])un_s;
  bf16(*kf_s)[16][SA] = (bf16(*)[16][SA])un_s;
  __shared__ __align__(16) bf16 vf_s[PTS][16][SA];
  __shared__ int js_s[PTS][16];

  if (t < PTS * 16) js_s[t >> 4][t & 15] = knn[(row0 + (t >> 4)) * KK + (t & 15)];
  __syncthreads();

  // ---- stage kf_s and vf_s via 16B vector loads (1024 chunks each) ----
#pragma unroll
  for (int i = 0; i < 4; ++i) {
    const int e = i * 256 + t;
    const int p = e >> 9, rem = e & 511;
    const int k = rem >> 5, ch = rem & 31;
    const size_t base = ((size_t)(b * NN + js_s[p][k])) * DD + ch * 8;
    *(bf16x8*)&kf_s[p][k][ch * 8] = *(const bf16x8*)(kfb + base);
    *(bf16x8*)&vf_s[p][k][ch * 8] = *(const bf16x8*)(vfb + base);
  }

  // ---- emb A-fragments computed per-lane in registers (no LDS) ----
  const float* xb = xyz + (size_t)b * NN * 3;
  bf16x8 ea0[PTS], ea1[PTS];
#pragma unroll
  for (int p = 0; p < PTS; ++p) {
    const int i = (row0 + p) & (NN - 1);
    const int j = js_s[p][m];  // this lane's neighbor row
    const float pd0 = xb[i * 3 + 0] - xb[j * 3 + 0];
    const float pd1 = xb[i * 3 + 1] - xb[j * 3 + 1];
    const float pd2 = xb[i * 3 + 2] - xb[j * 3 + 2];
#pragma unroll
    for (int jj = 0; jj < 8; ++jj) {
      ea0[p][jj] = (bf16)embval(qd * 8 + jj, pd0, pd1, pd2);
      ea1[p][jj] = (bf16)embval(32 + qd * 8 + jj, pd0, pd1, pd2);
    }
  }
  __syncthreads();  // staging visible

  // ---- phase B: pe MFMA -> bufA = q - kf_s + pe ; pe kept in regs ----
  float pe_r[4][PTS][4];
#pragma unroll
  for (int tt = 0; tt < 4; ++tt) {
    const int n = wv * 64 + tt * 16 + m;
    const bf16x8 b0 = *(const bf16x8*)(pwb + (size_t)n * 64 + qd * 8);
    const bf16x8 b1 = *(const bf16x8*)(pwb + (size_t)n * 64 + 32 + qd * 8);
    const float bias = pe_b[n];
#pragma unroll
    for (int p = 0; p < PTS; ++p) {
      f32x4 c = {bias, bias, bias, bias};
      c = __builtin_amdgcn_mfma_f32_16x16x32_bf16(ea0[p], b0, c, 0, 0, 0);
      c = __builtin_amdgcn_mfma_f32_16x16x32_bf16(ea1[p], b1, c, 0, 0, 0);
      const float qv = (float)qb[(size_t)(row0 + p) * DD + n];
#pragma unroll
      for (int rr = 0; rr < 4; ++rr) {
        const int krow = qd * 4 + rr;
        bufA[p][krow][n] = (bf16)(qv - (float)kf_s[p][krow][n] + c[rr]);
        pe_r[tt][p][rr] = c[rr];
      }
    }
  }
  __syncthreads();  // bufA ready; kf_s dead (union -> bufB safe)

  // ---- layer 1: h = relu(edges @ W1^T + b1), bufA -> bufB ----
  {
    bf16x8 afrag[PTS][8];
#pragma unroll
    for (int p = 0; p < PTS; ++p)
#pragma unroll
      for (int f = 0; f < 8; ++f)
        afrag[p][f] = *(const bf16x8*)&bufA[p][m][f * 32 + qd * 8];
    for (int tt = 0; tt < 4; ++tt) {
      const int n = wv * 64 + tt * 16 + m;
      bf16x8 bfr[8];
#pragma unroll
      for (int f = 0; f < 8; ++f)
        bfr[f] = *(const bf16x8*)(w1b + (size_t)n * DD + f * 32 + qd * 8);
      const float bias = g_b1[n];
#pragma unroll
      for (int p = 0; p < PTS; ++p) {
        f32x4 c = {bias, bias, bias, bias};
#pragma unroll
        for (int f = 0; f < 8; ++f)
          c = __builtin_amdgcn_mfma_f32_16x16x32_bf16(afrag[p][f], bfr[f], c, 0, 0, 0);
#pragma unroll
        for (int rr = 0; rr < 4; ++rr)
          bufB[p][qd * 4 + rr][n] = (bf16)fmaxf(c[rr], 0.f);
      }
    }
  }
  __syncthreads();

  // ---- layer 2 + softmax over k + combine (vf_s + pe_r) + BN stats ----
  {
    bf16x8 afrag[PTS][8];
#pragma unroll
    for (int p = 0; p < PTS; ++p)
#pragma unroll
      for (int f = 0; f < 8; ++f)
        afrag[p][f] = *(const bf16x8*)&bufB[p][m][f * 32 + qd * 8];
#pragma unroll
    for (int tt = 0; tt < 4; ++tt) {
      const int n = wv * 64 + tt * 16 + m;
      bf16x8 bfr[8];
#pragma unroll
      for (int f = 0; f < 8; ++f)
        bfr[f] = *(const bf16x8*)(w2b + (size_t)n * DD + f * 32 + qd * 8);
      const float bias = g_b2[n];
      float bs = 0.f, bs2 = 0.f;
#pragma unroll
      for (int p = 0; p < PTS; ++p) {
        f32x4 c = {bias, bias, bias, bias};
#pragma unroll
        for (int f = 0; f < 8; ++f)
          c = __builtin_amdgcn_mfma_f32_16x16x32_bf16(afrag[p][f], bfr[f], c, 0, 0, 0);
        float mx = fmaxf(fmaxf(c[0], c[1]), fmaxf(c[2], c[3]));
        mx = fmaxf(mx, __shfl_xor(mx, 16));
        mx = fmaxf(mx, __shfl_xor(mx, 32));
        float e[4], den = 0.f;
#pragma unroll
        for (int rr = 0; rr < 4; ++rr) {
          e[rr] = __expf(c[rr] - mx);
          den += e[rr];
        }
        den += __shfl_xor(den, 16);
        den += __shfl_xor(den, 32);
        float num = 0.f;
#pragma unroll
        for (int rr = 0; rr < 4; ++rr) {
          const float vpe =
              (float)vf_s[p][qd * 4 + rr][n] + pe_r[tt][p][rr];
          num += e[rr] * vpe;
        }
        num += __shfl_xor(num, 16);
        num += __shfl_xor(num, 32);
        if (qd == 0) {
          const size_t o = (size_t)(row0 + p) * DD + n;
          const float out = num / den + feats[o];
          res[o] = out;
          bs += out;
          bs2 += out * out;
        }
      }
      if (qd == 0) {
        atomicAdd(&sums[n], bs);
        atomicAdd(&sumsq[n], bs2);
      }
    }
  }
}

// ---------------------------------------------------------------------------
// BatchNorm apply (stats accumulated by edge_v9's epilogue)
// ---------------------------------------------------------------------------
__global__ __launch_bounds__(256) void bn_apply(float* __restrict__ out,
                                                const float* __restrict__ sums,
                                                const float* __restrict__ sumsq,
                                                const float* __restrict__ bn_w,
                                                const float* __restrict__ bn_b) {
  const int idx = blockIdx.x * 256 + threadIdx.x;
  const int c = idx & (DD - 1);
  const float inv_n = 1.f / (float)(BB * NN);
  const float mean = sums[c] * inv_n;
  const float var = sumsq[c] * inv_n - mean * mean;
  const float v = out[idx];
  out[idx] = (v - mean) * rsqrtf(var + 1e-5f) * bn_w[c] + bn_b[c];
}

extern "C" void kernel_launch(void* const* d_in, const int* in_sizes, int n_in,
                              void* d_out, int out_size, void* d_ws,
                              size_t ws_size, hipStream_t stream) {
  (void)in_sizes; (void)n_in; (void)out_size; (void)ws_size;
  const float* xyz = (const float*)d_in[0];
  const float* feats = (const float*)d_in[1];
  const float* w_q = (const float*)d_in[2];
  const float* w_k = (const float*)d_in[3];
  const float* w_v = (const float*)d_in[4];
  const float* g_w1 = (const float*)d_in[5];
  const float* g_b1 = (const float*)d_in[6];
  const float* g_w2 = (const float*)d_in[7];
  const float* g_b2 = (const float*)d_in[8];
  const float* pe_w = (const float*)d_in[9];
  const float* pe_b = (const float*)d_in[10];
  const float* bn_w = (const float*)d_in[11];
  const float* bn_b = (const float*)d_in[12];
  float* out = (float*)d_out;

  const int BN = BB * NN;  // 16384
  char* w = (char*)d_ws;
  int* knn = (int*)w;       w += (size_t)BN * KK * 4;
  bf16* qb = (bf16*)w;      w += (size_t)BN * DD * 2;
  bf16* kfb = (bf16*)w;     w += (size_t)BN * DD * 2;
  bf16* vfb = (bf16*)w;     w += (size_t)BN * DD * 2;
  float* sums = (float*)w;  w += DD * 4;
  float* sumsq = (float*)w; w += DD * 4;
  bf16* w1b = (bf16*)w;     w += (size_t)DD * DD * 2;
  bf16* w2b = (bf16*)w;     w += (size_t)DD * DD * 2;
  bf16* pwb = (bf16*)w;     w += (size_t)DD * 64 * 2;

  setup_kernel<<<KNNB + PROJB + PREPB, 256, 0, stream>>>(
      xyz, feats, w_q, w_k, w_v, g_w1, g_w2, pe_w, knn, qb, kfb, vfb, w1b, w2b,
      pwb, sums);
  edge_v9<<<BN / PTS, 256, 0, stream>>>(xyz, feats, qb, kfb, vfb, knn, w1b,
                                        g_b1, w2b, g_b2, pwb, pe_b, out, sums,
                                        sumsq);
  bn_apply<<<BN, 256, 0, stream>>>(out, sums, sumsq, bn_w, bn_b);
}